// Round 1
// baseline (389.697 us; speedup 1.0000x reference)
//
#include <hip/hip_runtime.h>
#include <math.h>

#define B 32
#define T 512
#define D 512
#define H 8
#define S 196
#define K_TOP 51      // int(0.1 * 512)
#define NCHUNK 8
#define LAYER_ID 2

// ---------------- K1: cosine weights, one wave (64 lanes) per (b,t) row ----
__global__ __launch_bounds__(256) void k_weights(const float* __restrict__ fore,
                                                 const float* __restrict__ te,
                                                 float* __restrict__ weights) {
    int row  = (blockIdx.x * blockDim.x + threadIdx.x) >> 6;   // global wave id
    int lane = threadIdx.x & 63;
    if (row >= B * T) return;
    int b = row >> 9;                                          // row / T
    const float4* xp = (const float4*)(te + (size_t)row * D);
    const float4* yp = (const float4*)(fore + (size_t)b * D);
    float4 x0 = xp[lane], x1 = xp[lane + 64];
    float4 y0 = yp[lane], y1 = yp[lane + 64];
    float xy = x0.x*y0.x + x0.y*y0.y + x0.z*y0.z + x0.w*y0.w
             + x1.x*y1.x + x1.y*y1.y + x1.z*y1.z + x1.w*y1.w;
    float xx = x0.x*x0.x + x0.y*x0.y + x0.z*x0.z + x0.w*x0.w
             + x1.x*x1.x + x1.y*x1.y + x1.z*x1.z + x1.w*x1.w;
    float yy = y0.x*y0.x + y0.y*y0.y + y0.z*y0.z + y0.w*y0.w
             + y1.x*y1.x + y1.y*y1.y + y1.z*y1.z + y1.w*y1.w;
    #pragma unroll
    for (int off = 32; off; off >>= 1) {
        xy += __shfl_xor(xy, off);
        xx += __shfl_xor(xx, off);
        yy += __shfl_xor(yy, off);
    }
    if (lane == 0) {
        float xn = fmaxf(sqrtf(xx), 1e-8f);
        float yn = fmaxf(sqrtf(yy), 1e-8f);
        weights[row] = xy / (xn * yn);
    }
}

// ---------------- K2: per-batch mask + seq_len + exact top-m selection -----
__global__ __launch_bounds__(512) void k_select(const int* __restrict__ targets,
                                                const float* __restrict__ weights,
                                                int* __restrict__ m_arr,
                                                int* __restrict__ sel_idx,
                                                float* __restrict__ sel_w,
                                                float* __restrict__ totals) {
    int b = blockIdx.x;
    int t = threadIdx.x;
    __shared__ float wsh[T];
    __shared__ int cnt, cnt2, mm;
    if (t == 0) { cnt = 0; cnt2 = 0; }
    __syncthreads();

    int tv = targets[b * (T + 1) + t];        // tgt = targets[:, :-1]
    bool mask = (t == 0) || (tv > 0);
    float w = weights[b * T + t];
    w = mask ? w : -1.0f;
    wsh[t] = w;

    unsigned long long bal = __ballot(mask);
    if ((t & 63) == 0) atomicAdd(&cnt, __popcll(bal));
    __syncthreads();

    if (t == 0) {
        int m = (int)ceilf((float)cnt * 0.1f);
        mm = m < K_TOP ? m : K_TOP;
        m_arr[b] = mm;
    }
    if (t < S) totals[b * S + t] = 0.0f;      // zero accumulator (ws is poisoned)
    __syncthreads();

    // rank with jax.lax.top_k tie-break (smaller index wins ties)
    float wt = w;
    int rank = 0;
    for (int j = 0; j < T; ++j) {
        float wj = wsh[j];
        rank += (wj > wt) || (wj == wt && j < t);
    }
    if (rank < mm) {
        int pos = atomicAdd(&cnt2, 1);        // order irrelevant: we sum all m
        sel_idx[b * 64 + pos] = t;
        sel_w [b * 64 + pos] = wt;
    }
}

// ---------------- K3: gather selected rows of align_attns[2], accumulate ---
__global__ __launch_bounds__(256) void k_accum(const float* __restrict__ align,
                                               const int* __restrict__ m_arr,
                                               const int* __restrict__ sel_idx,
                                               const float* __restrict__ sel_w,
                                               float* __restrict__ totals) {
    int b = blockIdx.y;
    int chunk = blockIdx.x;
    int s = threadIdx.x;
    if (s >= S) return;
    int m = m_arr[b];
    const float* base = align + ((size_t)(LAYER_ID * B + b)) * H * T * S;
    float acc = 0.0f;
    for (int i = chunk; i < m; i += NCHUNK) {
        int   t = sel_idx[b * 64 + i];
        float w = sel_w [b * 64 + i];
        const float* p = base + (size_t)t * S + s;
        float sum = 0.0f;
        #pragma unroll
        for (int h = 0; h < H; ++h) sum += p[(size_t)h * T * S];
        float v = w * (sum * (1.0f / H));
        acc += fmaxf(v, 0.0f);
    }
    atomicAdd(&totals[b * S + s], acc);
}

// ---------------- K4: divide by m, min/max normalize over S ----------------
__global__ __launch_bounds__(256) void k_norm(const float* __restrict__ totals,
                                              const int* __restrict__ m_arr,
                                              float* __restrict__ out) {
    int b = blockIdx.x;
    int s = threadIdx.x;
    __shared__ float smin[256], smax[256];
    float m = (float)m_arr[b];
    float v = (s < S) ? totals[b * S + s] / m : 0.0f;
    smin[s] = (s < S) ? v : 3.0e38f;
    smax[s] = (s < S) ? v : -3.0e38f;
    __syncthreads();
    #pragma unroll
    for (int off = 128; off; off >>= 1) {
        if (s < off) {
            smin[s] = fminf(smin[s], smin[s + off]);
            smax[s] = fmaxf(smax[s], smax[s + off]);
        }
        __syncthreads();
    }
    if (s < S) {
        float mn = smin[0], mx = smax[0];
        out[b * S + s] = (v - mn) / fmaxf(mx - mn, 1e-12f);
    }
}

extern "C" void kernel_launch(void* const* d_in, const int* in_sizes, int n_in,
                              void* d_out, int out_size, void* d_ws, size_t ws_size,
                              hipStream_t stream) {
    const float* fore    = (const float*)d_in[0];   // (B, D) f32
    const float* te      = (const float*)d_in[1];   // (B, T, D) f32
    const float* align   = (const float*)d_in[2];   // (L, B, H, T, S) f32
    const int*   targets = (const int*)d_in[3];     // (B, T+1) int32
    float* out = (float*)d_out;                     // (B, S) f32

    float* weights = (float*)d_ws;                  // B*T
    int*   m_arr   = (int*)(weights + B * T);       // B
    int*   sel_idx = m_arr + B;                     // B*64
    float* sel_w   = (float*)(sel_idx + B * 64);    // B*64
    float* totals  = sel_w + B * 64;                // B*S

    k_weights<<<dim3((B * T) / 4), 256, 0, stream>>>(fore, te, weights);
    k_select <<<dim3(B), 512, 0, stream>>>(targets, weights, m_arr, sel_idx, sel_w, totals);
    k_accum  <<<dim3(NCHUNK, B), 256, 0, stream>>>(align, m_arr, sel_idx, sel_w, totals);
    k_norm   <<<dim3(B), 256, 0, stream>>>(totals, m_arr, out);
}

// Round 2
// 389.159 us; speedup vs baseline: 1.0014x; 1.0014x over previous
//
#include <hip/hip_runtime.h>
#include <math.h>

#define B 32
#define T 512
#define D 512
#define H 8
#define S 196
#define K_TOP 51      // int(0.1 * 512)
#define NCHUNK 16
#define LAYER_ID 2

// ---------------- K1: cosine weights, one wave (64 lanes) per (b,t) row ----
__global__ __launch_bounds__(256) void k_weights(const float* __restrict__ fore,
                                                 const float* __restrict__ te,
                                                 float* __restrict__ weights) {
    int row  = (blockIdx.x * blockDim.x + threadIdx.x) >> 6;   // global wave id
    int lane = threadIdx.x & 63;
    if (row >= B * T) return;
    int b = row >> 9;                                          // row / T
    const float4* xp = (const float4*)(te + (size_t)row * D);
    const float4* yp = (const float4*)(fore + (size_t)b * D);
    float4 x0 = xp[lane], x1 = xp[lane + 64];
    float4 y0 = yp[lane], y1 = yp[lane + 64];
    float xy = x0.x*y0.x + x0.y*y0.y + x0.z*y0.z + x0.w*y0.w
             + x1.x*y1.x + x1.y*y1.y + x1.z*y1.z + x1.w*y1.w;
    float xx = x0.x*x0.x + x0.y*x0.y + x0.z*x0.z + x0.w*x0.w
             + x1.x*x1.x + x1.y*x1.y + x1.z*x1.z + x1.w*x1.w;
    float yy = y0.x*y0.x + y0.y*y0.y + y0.z*y0.z + y0.w*y0.w
             + y1.x*y1.x + y1.y*y1.y + y1.z*y1.z + y1.w*y1.w;
    #pragma unroll
    for (int off = 32; off; off >>= 1) {
        xy += __shfl_xor(xy, off);
        xx += __shfl_xor(xx, off);
        yy += __shfl_xor(yy, off);
    }
    if (lane == 0) {
        float xn = fmaxf(sqrtf(xx), 1e-8f);
        float yn = fmaxf(sqrtf(yy), 1e-8f);
        weights[row] = xy / (xn * yn);
    }
}

// ---------------- K2: per-batch mask + seq_len + exact top-m selection -----
// 256 threads; thread tid handles t0=tid and t1=tid+256, sharing each
// ds_read_b128 of the weight vector for both ranks.
__global__ __launch_bounds__(256) void k_select(const int* __restrict__ targets,
                                                const float* __restrict__ weights,
                                                int* __restrict__ m_arr,
                                                int* __restrict__ sel_idx,
                                                float* __restrict__ sel_w) {
    int b = blockIdx.x;
    int tid = threadIdx.x;
    __shared__ float wsh[T];
    __shared__ int cnt, cnt2, mm;
    if (tid == 0) { cnt = 0; cnt2 = 0; }
    __syncthreads();

    int t0 = tid, t1 = tid + 256;
    int tv0 = targets[b * (T + 1) + t0];
    int tv1 = targets[b * (T + 1) + t1];
    bool mk0 = (t0 == 0) || (tv0 > 0);
    bool mk1 = (tv1 > 0);
    float w0 = weights[b * T + t0]; w0 = mk0 ? w0 : -1.0f;
    float w1 = weights[b * T + t1]; w1 = mk1 ? w1 : -1.0f;
    wsh[t0] = w0;
    wsh[t1] = w1;

    unsigned long long bal0 = __ballot(mk0);
    unsigned long long bal1 = __ballot(mk1);
    if ((tid & 63) == 0) atomicAdd(&cnt, __popcll(bal0) + __popcll(bal1));
    __syncthreads();

    if (tid == 0) {
        int m = (int)ceilf((float)cnt * 0.1f);   // fp32, matches jnp exactly
        mm = m < K_TOP ? m : K_TOP;
        m_arr[b] = mm;
    }
    __syncthreads();

    // rank with jax.lax.top_k tie-break (smaller index wins ties)
    int r0 = 0, r1 = 0;
    const float4* w4 = (const float4*)wsh;
    for (int j4 = 0; j4 < T / 4; ++j4) {
        float4 v = w4[j4];                       // LDS broadcast, conflict-free
        int j = j4 * 4;
        r0 += (v.x > w0) || (v.x == w0 && (j + 0) < t0);
        r0 += (v.y > w0) || (v.y == w0 && (j + 1) < t0);
        r0 += (v.z > w0) || (v.z == w0 && (j + 2) < t0);
        r0 += (v.w > w0) || (v.w == w0 && (j + 3) < t0);
        r1 += (v.x > w1) || (v.x == w1 && (j + 0) < t1);
        r1 += (v.y > w1) || (v.y == w1 && (j + 1) < t1);
        r1 += (v.z > w1) || (v.z == w1 && (j + 2) < t1);
        r1 += (v.w > w1) || (v.w == w1 && (j + 3) < t1);
    }
    int lmm = mm;
    if (r0 < lmm) {
        int pos = atomicAdd(&cnt2, 1);           // order irrelevant: we sum all m
        sel_idx[b * 64 + pos] = t0;
        sel_w [b * 64 + pos] = w0;
    }
    if (r1 < lmm) {
        int pos = atomicAdd(&cnt2, 1);
        sel_idx[b * 64 + pos] = t1;
        sel_w [b * 64 + pos] = w1;
    }
}

// ---------------- K3: gather selected rows of align_attns[2] → partials ----
// No atomics: each (chunk,b) block writes its own partial row; K4 reduces.
__global__ __launch_bounds__(256) void k_accum(const float* __restrict__ align,
                                               const int* __restrict__ m_arr,
                                               const int* __restrict__ sel_idx,
                                               const float* __restrict__ sel_w,
                                               float* __restrict__ partials) {
    int b = blockIdx.y;
    int chunk = blockIdx.x;
    int s = threadIdx.x;
    if (s >= S) return;
    int m = m_arr[b];
    const float* base = align + ((size_t)(LAYER_ID * B + b)) * H * T * S;
    float acc = 0.0f;
    for (int i = chunk; i < m; i += NCHUNK) {
        int   t = sel_idx[b * 64 + i];
        float w = sel_w [b * 64 + i];
        const float* p = base + (size_t)t * S + s;
        float sum = 0.0f;
        #pragma unroll
        for (int h = 0; h < H; ++h) sum += p[(size_t)h * T * S];
        float v = w * (sum * (1.0f / H));
        acc += fmaxf(v, 0.0f);
    }
    partials[((size_t)b * NCHUNK + chunk) * S + s] = acc;   // unconditional (ws poisoned)
}

// ---------------- K4: reduce partials, /m, min-max normalize over S --------
__global__ __launch_bounds__(256) void k_norm(const float* __restrict__ partials,
                                              const int* __restrict__ m_arr,
                                              float* __restrict__ out) {
    int b = blockIdx.x;
    int s = threadIdx.x;
    __shared__ float smin[256], smax[256];
    float m = (float)m_arr[b];
    float v = 0.0f;
    if (s < S) {
        float tot = 0.0f;
        #pragma unroll
        for (int c = 0; c < NCHUNK; ++c)
            tot += partials[((size_t)b * NCHUNK + c) * S + s];
        v = tot / m;
    }
    smin[s] = (s < S) ? v : 3.0e38f;
    smax[s] = (s < S) ? v : -3.0e38f;
    __syncthreads();
    #pragma unroll
    for (int off = 128; off; off >>= 1) {
        if (s < off) {
            smin[s] = fminf(smin[s], smin[s + off]);
            smax[s] = fmaxf(smax[s], smax[s + off]);
        }
        __syncthreads();
    }
    if (s < S) {
        float mn = smin[0], mx = smax[0];
        out[b * S + s] = (v - mn) / fmaxf(mx - mn, 1e-12f);
    }
}

extern "C" void kernel_launch(void* const* d_in, const int* in_sizes, int n_in,
                              void* d_out, int out_size, void* d_ws, size_t ws_size,
                              hipStream_t stream) {
    const float* fore    = (const float*)d_in[0];   // (B, D) f32
    const float* te      = (const float*)d_in[1];   // (B, T, D) f32
    const float* align   = (const float*)d_in[2];   // (L, B, H, T, S) f32
    const int*   targets = (const int*)d_in[3];     // (B, T+1) int
    float* out = (float*)d_out;                     // (B, S) f32

    float* weights  = (float*)d_ws;                 // B*T
    int*   m_arr    = (int*)(weights + B * T);      // B
    int*   sel_idx  = m_arr + B;                    // B*64
    float* sel_w    = (float*)(sel_idx + B * 64);   // B*64
    float* partials = sel_w + B * 64;               // B*NCHUNK*S

    k_weights<<<dim3((B * T) / 4), 256, 0, stream>>>(fore, te, weights);
    k_select <<<dim3(B), 256, 0, stream>>>(targets, weights, m_arr, sel_idx, sel_w);
    k_accum  <<<dim3(NCHUNK, B), 256, 0, stream>>>(align, m_arr, sel_idx, sel_w, partials);
    k_norm   <<<dim3(B), 256, 0, stream>>>(partials, m_arr, out);
}